// Round 3
// baseline (143.705 us; speedup 1.0000x reference)
//
#include <hip/hip_runtime.h>
#include <math.h>

// CPNet registration: B=8 batches, pc1 (4 x 4096), pc2 (4 x 4096), fp32.
// Outputs: T (8,4,4)=128 | q (8,4)=32 | t (8,3)=24  -> 184 floats concat.
//
// R9: R8 structure kept verbatim (4 rows/thread, wave-split m-range,
// proven K2/K3/K4 tail). Hot loops rewritten with explicit inline-asm
// packed-FP32 ops (v_pk_fma_f32 / v_pk_add_f32, VOP3P register pairs):
// theory is the compiler scalarizes the v2f arithmetic, doubling VALU
// issue cycles (counter evidence: VALUBusy 73% at 60.7us matches the
// scalarized issue-count, not the packed one). min/max/rcp/sub/exp2
// remain scalar on the pair halves. Math is bit-identical to R8.

typedef float v2f __attribute__((ext_vector_type(2)));

// ---- packed-FP32 helpers (CDNA2+ VOP3P; operands are VGPR pairs) ----
__device__ __forceinline__ v2f pk_fma(v2f a, v2f b, v2f c) {
  v2f d;
  asm("v_pk_fma_f32 %0, %1, %2, %3" : "=v"(d) : "v"(a), "v"(b), "v"(c));
  return d;
}
__device__ __forceinline__ v2f pk_add(v2f a, v2f b) {
  v2f d;
  asm("v_pk_add_f32 %0, %1, %2" : "=v"(d) : "v"(a), "v"(b));
  return d;
}

constexpr int cB  = 8;
constexpr int cN1 = 4096;
constexpr int cN2 = 4096;
constexpr int cMC = 8;               // m-chunks
constexpr int cCHUNK = cN2 / cMC;    // 512
constexpr int cNB2 = cN1 / 256;      // 16 n-blocks for K2/K3
constexpr float cEPS  = 1e-5f;
constexpr float cKK   = 0.34657359027997264f;   // ln2/2 = 1/(FACT*log2(e))
constexpr float cEPSK = cEPS * cKK;             // scaled clamp
constexpr float cUNSC = -1.4426950408889634f;   // -1/ln2 (undo -ln2 packing)

// ---------------- workspace layout (bytes) ----------------
// partA : float4[cMC*cB*cN1] @ 0         (4 MiB; chunk 0 reused as near4)
// partM : float [cMC*cB*cN1] @ 0x400000  (1 MiB)
// dpart : double[cB*16]      @ 0x500000  (1 KiB)
// mpart : double[cB*16*23]   @ 0x500400  (29.4 KiB)
constexpr size_t OFF_PARTM = 0x400000;
constexpr size_t OFF_DPART = 0x500000;
constexpr size_t OFF_MPART = 0x500400;

// ============ K1: 4-rows/thread, wave-split m-range softmax partials =======
__global__ __launch_bounds__(256) void cpnet_partial(
    const float* __restrict__ pc1, const float* __restrict__ pc2,
    float4* __restrict__ partA, float* __restrict__ partM) {
  __shared__ float xs[cCHUNK], ys[cCHUNK], zs[cCHUNK], ws[cCHUNK];
  __shared__ float comb[4][256][5];   // [wave g][row][S,Ax,Ay,Az,M]
  const int tid = threadIdx.x;
  const int lane = tid & 63, g = tid >> 6;
  const int b = blockIdx.z, c = blockIdx.y;
  const int nbase = blockIdx.x * 256;

  // fused pack: (-ln2*x, -ln2*y, -ln2*z, (ln2/2)*|p|^2)
  const float* p2b = pc2 + (size_t)b * 4 * cN2 + c * cCHUNK;
  for (int i = tid; i < cCHUNK; i += 256) {
    float x = p2b[i], y = p2b[cN2 + i], z = p2b[2 * cN2 + i];
    xs[i] = -2.0f * cKK * x;
    ys[i] = -2.0f * cKK * y;
    zs[i] = -2.0f * cKK * z;
    ws[i] = cKK * (x * x + y * y + z * z);
  }
  __syncthreads();

  // 4 rows per thread: r = k*64 + lane (coalesced loads per k)
  const float* p1b = pc1 + (size_t)b * 4 * cN1;
  v2f X1[4], Y1[4], Z1[4], N1K[4];   // broadcast pairs for packed math
#pragma unroll
  for (int k = 0; k < 4; ++k) {
    int r = nbase + k * 64 + lane;
    float x = p1b[r], y = p1b[cN1 + r], z = p1b[2 * cN1 + r];
    float nk = cKK * (x * x + y * y + z * z);
    X1[k] = (v2f){x, x};
    Y1[k] = (v2f){y, y};
    Z1[k] = (v2f){z, z};
    N1K[k] = (v2f){nk, nk};
  }

  // wave g owns m in [g*128, g*128+128)  (64 v2f iterations)
  const v2f* xs2 = (const v2f*)xs + g * 64;
  const v2f* ys2 = (const v2f*)ys + g * 64;
  const v2f* zs2 = (const v2f*)zs + g * 64;
  const v2f* ws2 = (const v2f*)ws + g * 64;

  // pass 1: per-row min dk over this wave's sub-chunk
  float dminx[4], dminy[4];
#pragma unroll
  for (int k = 0; k < 4; ++k) { dminx[k] = 3.0e38f; dminy[k] = 3.0e38f; }
#pragma unroll 2
  for (int m = 0; m < 64; ++m) {
    v2f vx = xs2[m], vy = ys2[m], vz = zs2[m], vw = ws2[m];
#pragma unroll
    for (int k = 0; k < 4; ++k) {
      v2f t = pk_add(vw, N1K[k]);
      t = pk_fma(vz, Z1[k], t);
      t = pk_fma(vy, Y1[k], t);
      t = pk_fma(vx, X1[k], t);
      dminx[k] = fminf(dminx[k], t.x);
      dminy[k] = fminf(dminy[k], t.y);
    }
  }
  float M[4];
#pragma unroll
  for (int k = 0; k < 4; ++k)
    M[k] = __builtin_amdgcn_rcpf(fmaxf(fminf(dminx[k], dminy[k]), cEPSK));

  // pass 2: exp-sum + weighted accumulators relative to per-sub-chunk M
  v2f S2[4], Ax2[4], Ay2[4], Az2[4];
#pragma unroll
  for (int k = 0; k < 4; ++k) {
    S2[k] = (v2f){0.f, 0.f}; Ax2[k] = (v2f){0.f, 0.f};
    Ay2[k] = (v2f){0.f, 0.f}; Az2[k] = (v2f){0.f, 0.f};
  }
#pragma unroll 2
  for (int m = 0; m < 64; ++m) {
    v2f vx = xs2[m], vy = ys2[m], vz = zs2[m], vw = ws2[m];
#pragma unroll
    for (int k = 0; k < 4; ++k) {
      v2f t = pk_add(vw, N1K[k]);
      t = pk_fma(vz, Z1[k], t);
      t = pk_fma(vy, Y1[k], t);
      t = pk_fma(vx, X1[k], t);
      float dx = fmaxf(t.x, cEPSK);
      float dy = fmaxf(t.y, cEPSK);
      float sx = __builtin_amdgcn_rcpf(dx);
      float sy = __builtin_amdgcn_rcpf(dy);
      v2f e;
      e.x = __builtin_amdgcn_exp2f(sx - M[k]);
      e.y = __builtin_amdgcn_exp2f(sy - M[k]);
      S2[k]  = pk_add(S2[k], e);
      Ax2[k] = pk_fma(e, vx, Ax2[k]);
      Ay2[k] = pk_fma(e, vy, Ay2[k]);
      Az2[k] = pk_fma(e, vz, Az2[k]);
    }
  }

  // stash per-(wave, row) partials
#pragma unroll
  for (int k = 0; k < 4; ++k) {
    int r = k * 64 + lane;
    comb[g][r][0] = S2[k].x + S2[k].y;
    comb[g][r][1] = Ax2[k].x + Ax2[k].y;
    comb[g][r][2] = Ay2[k].x + Ay2[k].y;
    comb[g][r][3] = Az2[k].x + Az2[k].y;
    comb[g][r][4] = M[k];
  }
  __syncthreads();

  // per-row combine over the 4 waves (same rescale math as K2 cross-chunk)
  float m0 = comb[0][tid][4], m1 = comb[1][tid][4],
        m2 = comb[2][tid][4], m3 = comb[3][tid][4];
  float mrow = fmaxf(fmaxf(m0, m1), fmaxf(m2, m3));
  float S = 0.f, Ax = 0.f, Ay = 0.f, Az = 0.f;
#pragma unroll
  for (int gg = 0; gg < 4; ++gg) {
    float w = exp2f(comb[gg][tid][4] - mrow);
    S  += comb[gg][tid][0] * w;
    Ax += comb[gg][tid][1] * w;
    Ay += comb[gg][tid][2] * w;
    Az += comb[gg][tid][3] * w;
  }
  const int idx = (c * cB + b) * cN1 + nbase + tid;
  partA[idx] = make_float4(Ax, Ay, Az, S);
  partM[idx] = mrow;
}

// ---------------- batched block reduce (256 thr, 4 waves, doubles) ---------
__device__ __forceinline__ void reduce_multi(double* v, int nv, double* lds,
                                             int tid) {
  const int lane = tid & 63, w = tid >> 6;
  for (int i = 0; i < nv; ++i) {
    double x = v[i];
    for (int s = 32; s > 0; s >>= 1) x += __shfl_xor(x, s, 64);
    if (lane == 0) lds[i * 4 + w] = x;
  }
  __syncthreads();
  if (tid < nv)
    lds[tid * 4] = lds[tid * 4] + lds[tid * 4 + 1] + lds[tid * 4 + 2] +
                   lds[tid * 4 + 3];
  __syncthreads();
  for (int i = 0; i < nv; ++i) v[i] = lds[i * 4];
  __syncthreads();
}

// ============ K2: combine chunks -> near4 (aliased) + per-block dist sum ===
__global__ __launch_bounds__(256) void cpnet_combine(
    const float* __restrict__ pc1, float4* partA,
    const float* __restrict__ partM, double* __restrict__ dpart) {
  __shared__ double lds[32 * 4];
  const int tid = threadIdx.x;
  const int bx = blockIdx.x, b = blockIdx.y;
  const int n = bx * 256 + tid;

  float Ms[cMC];
  float g = -3.0e38f;
#pragma unroll
  for (int c = 0; c < cMC; ++c) {
    Ms[c] = partM[(c * cB + b) * cN1 + n];
    g = fmaxf(g, Ms[c]);
  }
  float S = 0.f, nx = 0.f, ny = 0.f, nz = 0.f;
#pragma unroll
  for (int c = 0; c < cMC; ++c) {
    float w = exp2f(Ms[c] - g);
    float4 a = partA[(c * cB + b) * cN1 + n];
    S += a.w * w; nx += a.x * w; ny += a.y * w; nz += a.z * w;
  }
  float inv = cUNSC / S;         // undo -ln2 packing + softmax normalize
  nx *= inv; ny *= inv; nz *= inv;
  const float* p1b = pc1 + (size_t)b * 4 * cN1;
  float dx = p1b[n] - nx, dy = p1b[cN1 + n] - ny, dz = p1b[2 * cN1 + n] - nz;
  float dist = sqrtf(dx * dx + dy * dy + dz * dz);
  // near4 alias: overwrite this row's chunk-0 slot (all reads of it done)
  partA[(0 * cB + b) * cN1 + n] = make_float4(nx, ny, nz, dist);

  double acc[1];
  acc[0] = (double)dist;
  reduce_multi(acc, 1, lds, tid);
  if (tid == 0) dpart[b * cNB2 + bx] = acc[0];
}

// ============ K3: inlier mask + 23 moments, per-block partials =============
__global__ __launch_bounds__(256) void cpnet_moments(
    const float* __restrict__ pc1, const float4* __restrict__ partA,
    const double* __restrict__ dpart, double* __restrict__ mpart) {
  __shared__ double lds[32 * 4];
  const int tid = threadIdx.x;
  const int bx = blockIdx.x, b = blockIdx.y;
  const int n = bx * 256 + tid;

  // deterministic mean: same serial sum in every block
  double dsum = 0.0;
  for (int i = 0; i < cNB2; ++i) dsum += dpart[b * cNB2 + i];
  const float meanf = (float)(dsum * (1.0 / (double)cN1));

  float4 nn = partA[(0 * cB + b) * cN1 + n];   // near4 alias
  float u = (nn.w - meanf - cEPS) * 1e10f;
  float ind = 1.0f / (1.0f + expf(u));
  const float* p1b = pc1 + (size_t)b * 4 * cN1;
  double di = (double)ind, di2 = di * di;
  double x1 = (double)p1b[n], y1 = (double)p1b[cN1 + n],
         z1 = (double)p1b[2 * cN1 + n];
  double x2 = (double)nn.x, y2 = (double)nn.y, z2 = (double)nn.z;

  double a[23];
  a[0] = di;
  a[1] = di * x1;  a[2] = di * y1;  a[3] = di * z1;
  a[4] = di * x2;  a[5] = di * y2;  a[6] = di * z2;
  a[7] = di2;
  a[8]  = di2 * x1;  a[9]  = di2 * y1;  a[10] = di2 * z1;
  a[11] = di2 * x2;  a[12] = di2 * y2;  a[13] = di2 * z2;
  a[14] = di2 * x1 * x2; a[15] = di2 * x1 * y2; a[16] = di2 * x1 * z2;
  a[17] = di2 * y1 * x2; a[18] = di2 * y1 * y2; a[19] = di2 * y1 * z2;
  a[20] = di2 * z1 * x2; a[21] = di2 * z1 * y2; a[22] = di2 * z1 * z2;

  reduce_multi(a, 23, lds, tid);
  if (tid == 0) {
    double* mb = mpart + (size_t)(b * cNB2 + bx) * 23;
    for (int i = 0; i < 23; ++i) mb[i] = a[i];
  }
}

// ============ K4: per-batch Kabsch solve (Horn quaternion, Jacobi) =========
__global__ __launch_bounds__(64) void cpnet_solve(
    const double* __restrict__ mpart, float* __restrict__ out) {
  const int b = blockIdx.x;
  if (threadIdx.x != 0) return;

  double acc[23];
  for (int i = 0; i < 23; ++i) acc[i] = 0.0;
  for (int k = 0; k < cNB2; ++k) {
    const double* mb = mpart + (size_t)(b * cNB2 + k) * 23;
    for (int i = 0; i < 23; ++i) acc[i] += mb[i];
  }

  double W = acc[0];
  double c1[3] = {acc[1] / W, acc[2] / W, acc[3] / W};
  double c2[3] = {acc[4] / W, acc[5] / W, acc[6] / W};
  double H[3][3];
  for (int i = 0; i < 3; ++i)
    for (int j = 0; j < 3; ++j)
      H[i][j] = acc[14 + 3 * i + j] - c2[j] * acc[8 + i] -
                c1[i] * acc[11 + j] + c1[i] * c2[j] * acc[7];

  // Horn / Besl-McKay 4x4 quaternion matrix -> Jacobi eigen (6 sweeps)
  double trH = H[0][0] + H[1][1] + H[2][2];
  double Nm[4][4], V[4][4];
  Nm[0][0] = trH;
  Nm[0][1] = Nm[1][0] = H[1][2] - H[2][1];
  Nm[0][2] = Nm[2][0] = H[2][0] - H[0][2];
  Nm[0][3] = Nm[3][0] = H[0][1] - H[1][0];
  Nm[1][1] = 2.0 * H[0][0] - trH;
  Nm[1][2] = Nm[2][1] = H[0][1] + H[1][0];
  Nm[1][3] = Nm[3][1] = H[0][2] + H[2][0];
  Nm[2][2] = 2.0 * H[1][1] - trH;
  Nm[2][3] = Nm[3][2] = H[1][2] + H[2][1];
  Nm[3][3] = 2.0 * H[2][2] - trH;

  for (int i = 0; i < 4; ++i)
    for (int j = 0; j < 4; ++j) V[i][j] = (i == j) ? 1.0 : 0.0;

  for (int sweep = 0; sweep < 6; ++sweep) {
    for (int p = 0; p < 3; ++p) {
      for (int q = p + 1; q < 4; ++q) {
        double apq = Nm[p][q];
        if (fabs(apq) < 1e-300) continue;
        double theta = (Nm[q][q] - Nm[p][p]) / (2.0 * apq);
        double tt = (theta >= 0.0 ? 1.0 : -1.0) /
                    (fabs(theta) + sqrt(theta * theta + 1.0));
        double cc = 1.0 / sqrt(tt * tt + 1.0);
        double ss = tt * cc;
        for (int k = 0; k < 4; ++k) {
          double akp = Nm[k][p], akq = Nm[k][q];
          Nm[k][p] = cc * akp - ss * akq;
          Nm[k][q] = ss * akp + cc * akq;
        }
        for (int k = 0; k < 4; ++k) {
          double apk = Nm[p][k], aqk = Nm[q][k];
          Nm[p][k] = cc * apk - ss * aqk;
          Nm[q][k] = ss * apk + cc * aqk;
        }
        for (int k = 0; k < 4; ++k) {
          double vkp = V[k][p], vkq = V[k][q];
          V[k][p] = cc * vkp - ss * vkq;
          V[k][q] = ss * vkp + cc * vkq;
        }
      }
    }
  }
  int imax = 0;
  for (int i = 1; i < 4; ++i)
    if (Nm[i][i] > Nm[imax][imax]) imax = i;
  double qw = V[0][imax], qx = V[1][imax], qy = V[2][imax], qz = V[3][imax];
  double qn = sqrt(qw * qw + qx * qx + qy * qy + qz * qz);
  qw /= qn; qx /= qn; qy /= qn; qz /= qn;

  double R[3][3];
  R[0][0] = 1.0 - 2.0 * (qy * qy + qz * qz);
  R[0][1] = 2.0 * (qx * qy - qw * qz);
  R[0][2] = 2.0 * (qx * qz + qw * qy);
  R[1][0] = 2.0 * (qx * qy + qw * qz);
  R[1][1] = 1.0 - 2.0 * (qx * qx + qz * qz);
  R[1][2] = 2.0 * (qy * qz - qw * qx);
  R[2][0] = 2.0 * (qx * qz - qw * qy);
  R[2][1] = 2.0 * (qy * qz + qw * qx);
  R[2][2] = 1.0 - 2.0 * (qx * qx + qy * qy);

  // safeguard vs convention flip: objective is tr(R H); transpose if better
  double tr1 = 0.0, tr2 = 0.0;
  for (int i = 0; i < 3; ++i)
    for (int j = 0; j < 3; ++j) {
      tr1 += R[i][j] * H[j][i];
      tr2 += R[j][i] * H[j][i];
    }
  if (tr2 > tr1) {
    for (int i = 0; i < 3; ++i)
      for (int j = i + 1; j < 3; ++j) {
        double tmp = R[i][j]; R[i][j] = R[j][i]; R[j][i] = tmp;
      }
  }

  double tx = c2[0] - (R[0][0] * c1[0] + R[0][1] * c1[1] + R[0][2] * c1[2]);
  double ty = c2[1] - (R[1][0] * c1[0] + R[1][1] * c1[1] + R[1][2] * c1[2]);
  double tz = c2[2] - (R[2][0] * c1[0] + R[2][1] * c1[1] + R[2][2] * c1[2]);

  auto sgn = [](double x) { return x >= 0.0 ? 1.0 : -1.0; };
  double oqw = 0.5 * sqrt(fmax(1.0 + R[0][0] + R[1][1] + R[2][2], 1e-12));
  double oqx = 0.5 * sqrt(fmax(1.0 + R[0][0] - R[1][1] - R[2][2], 1e-12)) *
               sgn(R[2][1] - R[1][2]);
  double oqy = 0.5 * sqrt(fmax(1.0 - R[0][0] + R[1][1] - R[2][2], 1e-12)) *
               sgn(R[0][2] - R[2][0]);
  double oqz = 0.5 * sqrt(fmax(1.0 - R[0][0] - R[1][1] + R[2][2], 1e-12)) *
               sgn(R[1][0] - R[0][1]);

  float* T = out + b * 16;
  T[0]  = (float)R[0][0]; T[1]  = (float)R[0][1]; T[2]  = (float)R[0][2]; T[3]  = (float)tx;
  T[4]  = (float)R[1][0]; T[5]  = (float)R[1][1]; T[6]  = (float)R[1][2]; T[7]  = (float)ty;
  T[8]  = (float)R[2][0]; T[9]  = (float)R[2][1]; T[10] = (float)R[2][2]; T[11] = (float)tz;
  T[12] = 0.f; T[13] = 0.f; T[14] = 0.f; T[15] = 1.f;
  float* Q = out + 128 + b * 4;
  Q[0] = (float)oqw; Q[1] = (float)oqx; Q[2] = (float)oqy; Q[3] = (float)oqz;
  float* Tt = out + 160 + b * 3;
  Tt[0] = (float)tx; Tt[1] = (float)ty; Tt[2] = (float)tz;
}

// ---------------- launch ----------------
extern "C" void kernel_launch(void* const* d_in, const int* in_sizes, int n_in,
                              void* d_out, int out_size, void* d_ws, size_t ws_size,
                              hipStream_t stream) {
  const float* pc1 = (const float*)d_in[0];
  const float* pc2 = (const float*)d_in[1];
  float* out = (float*)d_out;
  char* ws = (char*)d_ws;

  float4* partA = (float4*)ws;
  float*  partM = (float*)(ws + OFF_PARTM);
  double* dpart = (double*)(ws + OFF_DPART);
  double* mpart = (double*)(ws + OFF_MPART);

  cpnet_partial<<<dim3(cN1 / 256, cMC, cB), 256, 0, stream>>>(pc1, pc2,
                                                              partA, partM);
  cpnet_combine<<<dim3(cNB2, cB), 256, 0, stream>>>(pc1, partA, partM, dpart);
  cpnet_moments<<<dim3(cNB2, cB), 256, 0, stream>>>(pc1, partA, dpart, mpart);
  cpnet_solve<<<cB, 64, 0, stream>>>(mpart, out);
}

// Round 4
// 141.920 us; speedup vs baseline: 1.0126x; 1.0126x over previous
//
#include <hip/hip_runtime.h>
#include <math.h>

// CPNet registration: B=8 batches, pc1 (4 x 4096), pc2 (4 x 4096), fp32.
// Outputs: T (8,4,4)=128 | q (8,4)=32 | t (8,3)=24  -> 184 floats concat.
//
// R10: K1 reverted to R8's proven version (4 rows/thread, wave-split
// m-range, plain v2f ops -- 60.3us measured; R9's inline-asm packed ops
// REGRESSED to 67us, compiler was already packing). Tail collapsed:
// K2+K3+K4 -> ONE kernel, grid=8 (one block per batch, 512 threads,
// 8 rows/thread). Combine results stay in registers (no near4
// round-trip), mean via deterministic block reduce, 23 moments + block
// reduce, Horn/Jacobi solve on thread 0. No atomics, no cross-block
// deps, 2 launches total. dpart/mpart eliminated.

typedef float v2f __attribute__((ext_vector_type(2)));

constexpr int cB  = 8;
constexpr int cN1 = 4096;
constexpr int cN2 = 4096;
constexpr int cMC = 8;               // m-chunks
constexpr int cCHUNK = cN2 / cMC;    // 512
constexpr float cEPS  = 1e-5f;
constexpr float cKK   = 0.34657359027997264f;   // ln2/2 = 1/(FACT*log2(e))
constexpr float cEPSK = cEPS * cKK;             // scaled clamp
constexpr float cUNSC = -1.4426950408889634f;   // -1/ln2 (undo -ln2 packing)

// ---------------- workspace layout (bytes) ----------------
// partA : float4[cMC*cB*cN1] @ 0         (4 MiB)
// partM : float [cMC*cB*cN1] @ 0x400000  (1 MiB)
constexpr size_t OFF_PARTM = 0x400000;

// ============ K1: 4-rows/thread, wave-split m-range softmax partials =======
__global__ __launch_bounds__(256) void cpnet_partial(
    const float* __restrict__ pc1, const float* __restrict__ pc2,
    float4* __restrict__ partA, float* __restrict__ partM) {
  __shared__ float xs[cCHUNK], ys[cCHUNK], zs[cCHUNK], ws[cCHUNK];
  __shared__ float comb[4][256][5];   // [wave g][row][S,Ax,Ay,Az,M]
  const int tid = threadIdx.x;
  const int lane = tid & 63, g = tid >> 6;
  const int b = blockIdx.z, c = blockIdx.y;
  const int nbase = blockIdx.x * 256;

  // fused pack: (-ln2*x, -ln2*y, -ln2*z, (ln2/2)*|p|^2)
  const float* p2b = pc2 + (size_t)b * 4 * cN2 + c * cCHUNK;
  for (int i = tid; i < cCHUNK; i += 256) {
    float x = p2b[i], y = p2b[cN2 + i], z = p2b[2 * cN2 + i];
    xs[i] = -2.0f * cKK * x;
    ys[i] = -2.0f * cKK * y;
    zs[i] = -2.0f * cKK * z;
    ws[i] = cKK * (x * x + y * y + z * z);
  }
  __syncthreads();

  // 4 rows per thread: r = k*64 + lane (coalesced loads per k)
  const float* p1b = pc1 + (size_t)b * 4 * cN1;
  float x1[4], y1[4], z1[4], n1k[4];
#pragma unroll
  for (int k = 0; k < 4; ++k) {
    int r = nbase + k * 64 + lane;
    x1[k] = p1b[r];
    y1[k] = p1b[cN1 + r];
    z1[k] = p1b[2 * cN1 + r];
    n1k[k] = cKK * (x1[k] * x1[k] + y1[k] * y1[k] + z1[k] * z1[k]);
  }

  // wave g owns m in [g*128, g*128+128)  (64 v2f iterations)
  const v2f* xs2 = (const v2f*)xs + g * 64;
  const v2f* ys2 = (const v2f*)ys + g * 64;
  const v2f* zs2 = (const v2f*)zs + g * 64;
  const v2f* ws2 = (const v2f*)ws + g * 64;

  // pass 1: per-row min dk over this wave's sub-chunk
  v2f dmin2[4];
#pragma unroll
  for (int k = 0; k < 4; ++k) dmin2[k] = (v2f){3.0e38f, 3.0e38f};
#pragma unroll 2
  for (int m = 0; m < 64; ++m) {
    v2f vx = xs2[m], vy = ys2[m], vz = zs2[m], vw = ws2[m];
#pragma unroll
    for (int k = 0; k < 4; ++k) {
      v2f dk = vx * x1[k] + (vy * y1[k] + (vz * z1[k] + (vw + n1k[k])));
      dmin2[k] = __builtin_elementwise_min(dmin2[k], dk);
    }
  }
  float M[4];
#pragma unroll
  for (int k = 0; k < 4; ++k)
    M[k] = __builtin_amdgcn_rcpf(fmaxf(fminf(dmin2[k].x, dmin2[k].y), cEPSK));

  // pass 2: exp-sum + weighted accumulators relative to per-sub-chunk M
  v2f S2[4], Ax2[4], Ay2[4], Az2[4];
#pragma unroll
  for (int k = 0; k < 4; ++k) {
    S2[k] = (v2f){0.f, 0.f}; Ax2[k] = (v2f){0.f, 0.f};
    Ay2[k] = (v2f){0.f, 0.f}; Az2[k] = (v2f){0.f, 0.f};
  }
  const v2f EPS2 = {cEPSK, cEPSK};
#pragma unroll 2
  for (int m = 0; m < 64; ++m) {
    v2f vx = xs2[m], vy = ys2[m], vz = zs2[m], vw = ws2[m];
#pragma unroll
    for (int k = 0; k < 4; ++k) {
      v2f dk = vx * x1[k] + (vy * y1[k] + (vz * z1[k] + (vw + n1k[k])));
      dk = __builtin_elementwise_max(dk, EPS2);
      v2f s2v;
      s2v.x = __builtin_amdgcn_rcpf(dk.x);
      s2v.y = __builtin_amdgcn_rcpf(dk.y);
      v2f e;
      e.x = __builtin_amdgcn_exp2f(s2v.x - M[k]);
      e.y = __builtin_amdgcn_exp2f(s2v.y - M[k]);
      S2[k] += e;
      Ax2[k] += e * vx;
      Ay2[k] += e * vy;
      Az2[k] += e * vz;
    }
  }

  // stash per-(wave, row) partials
#pragma unroll
  for (int k = 0; k < 4; ++k) {
    int r = k * 64 + lane;
    comb[g][r][0] = S2[k].x + S2[k].y;
    comb[g][r][1] = Ax2[k].x + Ax2[k].y;
    comb[g][r][2] = Ay2[k].x + Ay2[k].y;
    comb[g][r][3] = Az2[k].x + Az2[k].y;
    comb[g][r][4] = M[k];
  }
  __syncthreads();

  // per-row combine over the 4 waves (same rescale math as tail cross-chunk)
  float m0 = comb[0][tid][4], m1 = comb[1][tid][4],
        m2 = comb[2][tid][4], m3 = comb[3][tid][4];
  float mrow = fmaxf(fmaxf(m0, m1), fmaxf(m2, m3));
  float S = 0.f, Ax = 0.f, Ay = 0.f, Az = 0.f;
#pragma unroll
  for (int gg = 0; gg < 4; ++gg) {
    float w = exp2f(comb[gg][tid][4] - mrow);
    S  += comb[gg][tid][0] * w;
    Ax += comb[gg][tid][1] * w;
    Ay += comb[gg][tid][2] * w;
    Az += comb[gg][tid][3] * w;
  }
  const int idx = (c * cB + b) * cN1 + nbase + tid;
  partA[idx] = make_float4(Ax, Ay, Az, S);
  partM[idx] = mrow;
}

// ============ K2': fused combine + mean + moments + solve, 1 block/batch ===
__global__ __launch_bounds__(512) void cpnet_tail(
    const float* __restrict__ pc1, const float4* __restrict__ partA,
    const float* __restrict__ partM, float* __restrict__ out) {
  __shared__ double lds[23 * 8];
  __shared__ float s_mean;
  const int tid = threadIdx.x;
  const int lane = tid & 63, w = tid >> 6;   // 8 waves
  const int b = blockIdx.x;
  const float* p1b = pc1 + (size_t)b * 4 * cN1;

  // ---------- phase A: combine (K2 math verbatim), results in registers ----
  float nxr[8], nyr[8], nzr[8], dr[8];
  double dsum = 0.0;
#pragma unroll
  for (int k = 0; k < 8; ++k) {
    const int n = k * 512 + tid;
    float Ms[cMC];
    float g = -3.0e38f;
#pragma unroll
    for (int c = 0; c < cMC; ++c) {
      Ms[c] = partM[(c * cB + b) * cN1 + n];
      g = fmaxf(g, Ms[c]);
    }
    float S = 0.f, nx = 0.f, ny = 0.f, nz = 0.f;
#pragma unroll
    for (int c = 0; c < cMC; ++c) {
      float wgt = exp2f(Ms[c] - g);
      float4 a4 = partA[(c * cB + b) * cN1 + n];
      S += a4.w * wgt; nx += a4.x * wgt; ny += a4.y * wgt; nz += a4.z * wgt;
    }
    float inv = cUNSC / S;       // undo -ln2 packing + softmax normalize
    nx *= inv; ny *= inv; nz *= inv;
    float dx = p1b[n] - nx, dy = p1b[cN1 + n] - ny, dz = p1b[2 * cN1 + n] - nz;
    float dist = sqrtf(dx * dx + dy * dy + dz * dz);
    nxr[k] = nx; nyr[k] = ny; nzr[k] = nz; dr[k] = dist;
    dsum += (double)dist;
  }

  // ---------- phase B: mean via deterministic block reduce ----------
  {
    double x = dsum;
    for (int s = 32; s > 0; s >>= 1) x += __shfl_xor(x, s, 64);
    if (lane == 0) lds[w] = x;
  }
  __syncthreads();
  if (tid == 0) {
    double t = 0.0;
    for (int i = 0; i < 8; ++i) t += lds[i];
    s_mean = (float)(t * (1.0 / (double)cN1));
  }
  __syncthreads();
  const float meanf = s_mean;

  // ---------- phase C: 23 moments over this thread's 8 rows ----------
  double a[23];
  for (int i = 0; i < 23; ++i) a[i] = 0.0;
#pragma unroll
  for (int k = 0; k < 8; ++k) {
    const int n = k * 512 + tid;
    float u = (dr[k] - meanf - cEPS) * 1e10f;
    float ind = 1.0f / (1.0f + expf(u));
    double di = (double)ind, di2 = di * di;
    double x1 = (double)p1b[n], y1 = (double)p1b[cN1 + n],
           z1 = (double)p1b[2 * cN1 + n];
    double x2 = (double)nxr[k], y2 = (double)nyr[k], z2 = (double)nzr[k];

    a[0] += di;
    a[1] += di * x1;  a[2] += di * y1;  a[3] += di * z1;
    a[4] += di * x2;  a[5] += di * y2;  a[6] += di * z2;
    a[7] += di2;
    a[8]  += di2 * x1;  a[9]  += di2 * y1;  a[10] += di2 * z1;
    a[11] += di2 * x2;  a[12] += di2 * y2;  a[13] += di2 * z2;
    a[14] += di2 * x1 * x2; a[15] += di2 * x1 * y2; a[16] += di2 * x1 * z2;
    a[17] += di2 * y1 * x2; a[18] += di2 * y1 * y2; a[19] += di2 * y1 * z2;
    a[20] += di2 * z1 * x2; a[21] += di2 * z1 * y2; a[22] += di2 * z1 * z2;
  }

  // ---------- phase D: block reduce the 23 moments ----------
  for (int i = 0; i < 23; ++i) {
    double x = a[i];
    for (int s = 32; s > 0; s >>= 1) x += __shfl_xor(x, s, 64);
    if (lane == 0) lds[i * 8 + w] = x;
  }
  __syncthreads();
  if (tid < 23) {
    double t = 0.0;
    for (int j = 0; j < 8; ++j) t += lds[tid * 8 + j];
    lds[tid * 8] = t;
  }
  __syncthreads();

  // ---------- phase E: Kabsch solve (Horn quaternion, Jacobi), thread 0 ----
  if (tid != 0) return;

  double acc[23];
  for (int i = 0; i < 23; ++i) acc[i] = lds[i * 8];

  double W = acc[0];
  double c1[3] = {acc[1] / W, acc[2] / W, acc[3] / W};
  double c2[3] = {acc[4] / W, acc[5] / W, acc[6] / W};
  double H[3][3];
  for (int i = 0; i < 3; ++i)
    for (int j = 0; j < 3; ++j)
      H[i][j] = acc[14 + 3 * i + j] - c2[j] * acc[8 + i] -
                c1[i] * acc[11 + j] + c1[i] * c2[j] * acc[7];

  // Horn / Besl-McKay 4x4 quaternion matrix -> Jacobi eigen (6 sweeps)
  double trH = H[0][0] + H[1][1] + H[2][2];
  double Nm[4][4], V[4][4];
  Nm[0][0] = trH;
  Nm[0][1] = Nm[1][0] = H[1][2] - H[2][1];
  Nm[0][2] = Nm[2][0] = H[2][0] - H[0][2];
  Nm[0][3] = Nm[3][0] = H[0][1] - H[1][0];
  Nm[1][1] = 2.0 * H[0][0] - trH;
  Nm[1][2] = Nm[2][1] = H[0][1] + H[1][0];
  Nm[1][3] = Nm[3][1] = H[0][2] + H[2][0];
  Nm[2][2] = 2.0 * H[1][1] - trH;
  Nm[2][3] = Nm[3][2] = H[1][2] + H[2][1];
  Nm[3][3] = 2.0 * H[2][2] - trH;

  for (int i = 0; i < 4; ++i)
    for (int j = 0; j < 4; ++j) V[i][j] = (i == j) ? 1.0 : 0.0;

  for (int sweep = 0; sweep < 6; ++sweep) {
    for (int p = 0; p < 3; ++p) {
      for (int q = p + 1; q < 4; ++q) {
        double apq = Nm[p][q];
        if (fabs(apq) < 1e-300) continue;
        double theta = (Nm[q][q] - Nm[p][p]) / (2.0 * apq);
        double tt = (theta >= 0.0 ? 1.0 : -1.0) /
                    (fabs(theta) + sqrt(theta * theta + 1.0));
        double cc = 1.0 / sqrt(tt * tt + 1.0);
        double ss = tt * cc;
        for (int k = 0; k < 4; ++k) {
          double akp = Nm[k][p], akq = Nm[k][q];
          Nm[k][p] = cc * akp - ss * akq;
          Nm[k][q] = ss * akp + cc * akq;
        }
        for (int k = 0; k < 4; ++k) {
          double apk = Nm[p][k], aqk = Nm[q][k];
          Nm[p][k] = cc * apk - ss * aqk;
          Nm[q][k] = ss * apk + cc * aqk;
        }
        for (int k = 0; k < 4; ++k) {
          double vkp = V[k][p], vkq = V[k][q];
          V[k][p] = cc * vkp - ss * vkq;
          V[k][q] = ss * vkp + cc * vkq;
        }
      }
    }
  }
  int imax = 0;
  for (int i = 1; i < 4; ++i)
    if (Nm[i][i] > Nm[imax][imax]) imax = i;
  double qw = V[0][imax], qx = V[1][imax], qy = V[2][imax], qz = V[3][imax];
  double qn = sqrt(qw * qw + qx * qx + qy * qy + qz * qz);
  qw /= qn; qx /= qn; qy /= qn; qz /= qn;

  double R[3][3];
  R[0][0] = 1.0 - 2.0 * (qy * qy + qz * qz);
  R[0][1] = 2.0 * (qx * qy - qw * qz);
  R[0][2] = 2.0 * (qx * qz + qw * qy);
  R[1][0] = 2.0 * (qx * qy + qw * qz);
  R[1][1] = 1.0 - 2.0 * (qx * qx + qz * qz);
  R[1][2] = 2.0 * (qy * qz - qw * qx);
  R[2][0] = 2.0 * (qx * qz - qw * qy);
  R[2][1] = 2.0 * (qy * qz + qw * qx);
  R[2][2] = 1.0 - 2.0 * (qx * qx + qy * qy);

  // safeguard vs convention flip: objective is tr(R H); transpose if better
  double tr1 = 0.0, tr2 = 0.0;
  for (int i = 0; i < 3; ++i)
    for (int j = 0; j < 3; ++j) {
      tr1 += R[i][j] * H[j][i];
      tr2 += R[j][i] * H[j][i];
    }
  if (tr2 > tr1) {
    for (int i = 0; i < 3; ++i)
      for (int j = i + 1; j < 3; ++j) {
        double tmp = R[i][j]; R[i][j] = R[j][i]; R[j][i] = tmp;
      }
  }

  double tx = c2[0] - (R[0][0] * c1[0] + R[0][1] * c1[1] + R[0][2] * c1[2]);
  double ty = c2[1] - (R[1][0] * c1[0] + R[1][1] * c1[1] + R[1][2] * c1[2]);
  double tz = c2[2] - (R[2][0] * c1[0] + R[2][1] * c1[1] + R[2][2] * c1[2]);

  auto sgn = [](double x) { return x >= 0.0 ? 1.0 : -1.0; };
  double oqw = 0.5 * sqrt(fmax(1.0 + R[0][0] + R[1][1] + R[2][2], 1e-12));
  double oqx = 0.5 * sqrt(fmax(1.0 + R[0][0] - R[1][1] - R[2][2], 1e-12)) *
               sgn(R[2][1] - R[1][2]);
  double oqy = 0.5 * sqrt(fmax(1.0 - R[0][0] + R[1][1] - R[2][2], 1e-12)) *
               sgn(R[0][2] - R[2][0]);
  double oqz = 0.5 * sqrt(fmax(1.0 - R[0][0] - R[1][1] + R[2][2], 1e-12)) *
               sgn(R[1][0] - R[0][1]);

  float* T = out + b * 16;
  T[0]  = (float)R[0][0]; T[1]  = (float)R[0][1]; T[2]  = (float)R[0][2]; T[3]  = (float)tx;
  T[4]  = (float)R[1][0]; T[5]  = (float)R[1][1]; T[6]  = (float)R[1][2]; T[7]  = (float)ty;
  T[8]  = (float)R[2][0]; T[9]  = (float)R[2][1]; T[10] = (float)R[2][2]; T[11] = (float)tz;
  T[12] = 0.f; T[13] = 0.f; T[14] = 0.f; T[15] = 1.f;
  float* Q = out + 128 + b * 4;
  Q[0] = (float)oqw; Q[1] = (float)oqx; Q[2] = (float)oqy; Q[3] = (float)oqz;
  float* Tt = out + 160 + b * 3;
  Tt[0] = (float)tx; Tt[1] = (float)ty; Tt[2] = (float)tz;
}

// ---------------- launch ----------------
extern "C" void kernel_launch(void* const* d_in, const int* in_sizes, int n_in,
                              void* d_out, int out_size, void* d_ws, size_t ws_size,
                              hipStream_t stream) {
  const float* pc1 = (const float*)d_in[0];
  const float* pc2 = (const float*)d_in[1];
  float* out = (float*)d_out;
  char* ws = (char*)d_ws;

  float4* partA = (float4*)ws;
  float*  partM = (float*)(ws + OFF_PARTM);

  cpnet_partial<<<dim3(cN1 / 256, cMC, cB), 256, 0, stream>>>(pc1, pc2,
                                                              partA, partM);
  cpnet_tail<<<cB, 512, 0, stream>>>(pc1, partA, partM, out);
}

// Round 5
// 137.056 us; speedup vs baseline: 1.0485x; 1.0355x over previous
//
#include <hip/hip_runtime.h>
#include <math.h>

// CPNet registration: B=8 batches, pc1 (4 x 4096), pc2 (4 x 4096), fp32.
// Outputs: T (8,4,4)=128 | q (8,4)=32 | t (8,3)=24  -> 184 floats concat.
//
// R11: two fixes driven by the R6/R8/R10 tail-invariance analysis:
// (1) K1 occupancy: blocks now cover 128 rows (2 rows/thread; per-wave
//     m-partition of the 512-chunk UNCHANGED -> partA/partM bit-identical
//     to R8), grid 1024->2048 blocks (8/CU), LDS 28.6->18 KB,
//     __launch_bounds__(256,8). Attacks the 28% VALU-stall gap.
// (2) Tail shaped by bandwidth: combine stays WIDE (128 blocks, proven
//     K2 verbatim, reads the 5 MB of partials), moments+solve fused into
//     one NARROW kernel (8 blocks; reads only near4+pc1 = 112 KB/batch,
//     mean via the same deterministic serial-16 dpart sum, block-reduce
//     of 23 moments, Horn/Jacobi solve on tid 0). mpart round-trip and
//     K4's serial 368-double-load accumulation eliminated. 3 dispatches.

typedef float v2f __attribute__((ext_vector_type(2)));

constexpr int cB  = 8;
constexpr int cN1 = 4096;
constexpr int cN2 = 4096;
constexpr int cMC = 8;               // m-chunks
constexpr int cCHUNK = cN2 / cMC;    // 512
constexpr int cROWS = 128;           // rows per K1 block
constexpr int cNB2 = cN1 / 256;      // 16 n-blocks for K2
constexpr float cEPS  = 1e-5f;
constexpr float cKK   = 0.34657359027997264f;   // ln2/2 = 1/(FACT*log2(e))
constexpr float cEPSK = cEPS * cKK;             // scaled clamp
constexpr float cUNSC = -1.4426950408889634f;   // -1/ln2 (undo -ln2 packing)

// ---------------- workspace layout (bytes) ----------------
// partA : float4[cMC*cB*cN1] @ 0         (4 MiB; chunk 0 reused as near4)
// partM : float [cMC*cB*cN1] @ 0x400000  (1 MiB)
// dpart : double[cB*16]      @ 0x500000  (1 KiB)
constexpr size_t OFF_PARTM = 0x400000;
constexpr size_t OFF_DPART = 0x500000;

// ============ K1: 2-rows/thread, wave-split m-range softmax partials =======
__global__ __launch_bounds__(256, 8) void cpnet_partial(
    const float* __restrict__ pc1, const float* __restrict__ pc2,
    float4* __restrict__ partA, float* __restrict__ partM) {
  __shared__ float xs[cCHUNK], ys[cCHUNK], zs[cCHUNK], ws[cCHUNK];
  __shared__ float comb[4][cROWS][5];   // [wave g][row][S,Ax,Ay,Az,M]
  const int tid = threadIdx.x;
  const int lane = tid & 63, g = tid >> 6;
  const int b = blockIdx.z, c = blockIdx.y;
  const int nbase = blockIdx.x * cROWS;

  // fused pack: (-ln2*x, -ln2*y, -ln2*z, (ln2/2)*|p|^2)
  const float* p2b = pc2 + (size_t)b * 4 * cN2 + c * cCHUNK;
  for (int i = tid; i < cCHUNK; i += 256) {
    float x = p2b[i], y = p2b[cN2 + i], z = p2b[2 * cN2 + i];
    xs[i] = -2.0f * cKK * x;
    ys[i] = -2.0f * cKK * y;
    zs[i] = -2.0f * cKK * z;
    ws[i] = cKK * (x * x + y * y + z * z);
  }
  __syncthreads();

  // 2 rows per thread: r = k*64 + lane (coalesced loads per k)
  const float* p1b = pc1 + (size_t)b * 4 * cN1;
  float x1[2], y1[2], z1[2], n1k[2];
#pragma unroll
  for (int k = 0; k < 2; ++k) {
    int r = nbase + k * 64 + lane;
    x1[k] = p1b[r];
    y1[k] = p1b[cN1 + r];
    z1[k] = p1b[2 * cN1 + r];
    n1k[k] = cKK * (x1[k] * x1[k] + y1[k] * y1[k] + z1[k] * z1[k]);
  }

  // wave g owns m in [g*128, g*128+128)  (64 v2f iterations) -- unchanged
  const v2f* xs2 = (const v2f*)xs + g * 64;
  const v2f* ys2 = (const v2f*)ys + g * 64;
  const v2f* zs2 = (const v2f*)zs + g * 64;
  const v2f* ws2 = (const v2f*)ws + g * 64;

  // pass 1: per-row min dk over this wave's sub-chunk
  v2f dmin2[2];
#pragma unroll
  for (int k = 0; k < 2; ++k) dmin2[k] = (v2f){3.0e38f, 3.0e38f};
#pragma unroll 4
  for (int m = 0; m < 64; ++m) {
    v2f vx = xs2[m], vy = ys2[m], vz = zs2[m], vw = ws2[m];
#pragma unroll
    for (int k = 0; k < 2; ++k) {
      v2f dk = vx * x1[k] + (vy * y1[k] + (vz * z1[k] + (vw + n1k[k])));
      dmin2[k] = __builtin_elementwise_min(dmin2[k], dk);
    }
  }
  float M[2];
#pragma unroll
  for (int k = 0; k < 2; ++k)
    M[k] = __builtin_amdgcn_rcpf(fmaxf(fminf(dmin2[k].x, dmin2[k].y), cEPSK));

  // pass 2: exp-sum + weighted accumulators relative to per-sub-chunk M
  v2f S2[2], Ax2[2], Ay2[2], Az2[2];
#pragma unroll
  for (int k = 0; k < 2; ++k) {
    S2[k] = (v2f){0.f, 0.f}; Ax2[k] = (v2f){0.f, 0.f};
    Ay2[k] = (v2f){0.f, 0.f}; Az2[k] = (v2f){0.f, 0.f};
  }
  const v2f EPS2 = {cEPSK, cEPSK};
#pragma unroll 4
  for (int m = 0; m < 64; ++m) {
    v2f vx = xs2[m], vy = ys2[m], vz = zs2[m], vw = ws2[m];
#pragma unroll
    for (int k = 0; k < 2; ++k) {
      v2f dk = vx * x1[k] + (vy * y1[k] + (vz * z1[k] + (vw + n1k[k])));
      dk = __builtin_elementwise_max(dk, EPS2);
      v2f s2v;
      s2v.x = __builtin_amdgcn_rcpf(dk.x);
      s2v.y = __builtin_amdgcn_rcpf(dk.y);
      v2f e;
      e.x = __builtin_amdgcn_exp2f(s2v.x - M[k]);
      e.y = __builtin_amdgcn_exp2f(s2v.y - M[k]);
      S2[k] += e;
      Ax2[k] += e * vx;
      Ay2[k] += e * vy;
      Az2[k] += e * vz;
    }
  }

  // stash per-(wave, row) partials
#pragma unroll
  for (int k = 0; k < 2; ++k) {
    int r = k * 64 + lane;
    comb[g][r][0] = S2[k].x + S2[k].y;
    comb[g][r][1] = Ax2[k].x + Ax2[k].y;
    comb[g][r][2] = Ay2[k].x + Ay2[k].y;
    comb[g][r][3] = Az2[k].x + Az2[k].y;
    comb[g][r][4] = M[k];
  }
  __syncthreads();

  // per-row combine over the 4 waves (same rescale math as K2 cross-chunk)
  if (tid < cROWS) {
    float m0 = comb[0][tid][4], m1 = comb[1][tid][4],
          m2 = comb[2][tid][4], m3 = comb[3][tid][4];
    float mrow = fmaxf(fmaxf(m0, m1), fmaxf(m2, m3));
    float S = 0.f, Ax = 0.f, Ay = 0.f, Az = 0.f;
#pragma unroll
    for (int gg = 0; gg < 4; ++gg) {
      float w = exp2f(comb[gg][tid][4] - mrow);
      S  += comb[gg][tid][0] * w;
      Ax += comb[gg][tid][1] * w;
      Ay += comb[gg][tid][2] * w;
      Az += comb[gg][tid][3] * w;
    }
    const int idx = (c * cB + b) * cN1 + nbase + tid;
    partA[idx] = make_float4(Ax, Ay, Az, S);
    partM[idx] = mrow;
  }
}

// ---------------- batched block reduce (256 thr, 4 waves, doubles) ---------
__device__ __forceinline__ void reduce_multi(double* v, int nv, double* lds,
                                             int tid) {
  const int lane = tid & 63, w = tid >> 6;
  for (int i = 0; i < nv; ++i) {
    double x = v[i];
    for (int s = 32; s > 0; s >>= 1) x += __shfl_xor(x, s, 64);
    if (lane == 0) lds[i * 4 + w] = x;
  }
  __syncthreads();
  if (tid < nv)
    lds[tid * 4] = lds[tid * 4] + lds[tid * 4 + 1] + lds[tid * 4 + 2] +
                   lds[tid * 4 + 3];
  __syncthreads();
  for (int i = 0; i < nv; ++i) v[i] = lds[i * 4];
  __syncthreads();
}

// ============ K2: combine chunks -> near4 (aliased) + per-block dist sum ===
__global__ __launch_bounds__(256) void cpnet_combine(
    const float* __restrict__ pc1, float4* partA,
    const float* __restrict__ partM, double* __restrict__ dpart) {
  __shared__ double lds[32 * 4];
  const int tid = threadIdx.x;
  const int bx = blockIdx.x, b = blockIdx.y;
  const int n = bx * 256 + tid;

  float Ms[cMC];
  float g = -3.0e38f;
#pragma unroll
  for (int c = 0; c < cMC; ++c) {
    Ms[c] = partM[(c * cB + b) * cN1 + n];
    g = fmaxf(g, Ms[c]);
  }
  float S = 0.f, nx = 0.f, ny = 0.f, nz = 0.f;
#pragma unroll
  for (int c = 0; c < cMC; ++c) {
    float w = exp2f(Ms[c] - g);
    float4 a = partA[(c * cB + b) * cN1 + n];
    S += a.w * w; nx += a.x * w; ny += a.y * w; nz += a.z * w;
  }
  float inv = cUNSC / S;         // undo -ln2 packing + softmax normalize
  nx *= inv; ny *= inv; nz *= inv;
  const float* p1b = pc1 + (size_t)b * 4 * cN1;
  float dx = p1b[n] - nx, dy = p1b[cN1 + n] - ny, dz = p1b[2 * cN1 + n] - nz;
  float dist = sqrtf(dx * dx + dy * dy + dz * dz);
  // near4 alias: overwrite this row's chunk-0 slot (all reads of it done)
  partA[(0 * cB + b) * cN1 + n] = make_float4(nx, ny, nz, dist);

  double acc[1];
  acc[0] = (double)dist;
  reduce_multi(acc, 1, lds, tid);
  if (tid == 0) dpart[b * cNB2 + bx] = acc[0];
}

// ============ K3: mean + inlier mask + 23 moments + Kabsch solve ===========
__global__ __launch_bounds__(256) void cpnet_moments_solve(
    const float* __restrict__ pc1, const float4* __restrict__ partA,
    const double* __restrict__ dpart, float* __restrict__ out) {
  __shared__ double lds[23 * 4];
  const int tid = threadIdx.x;
  const int b = blockIdx.x;
  const float* p1b = pc1 + (size_t)b * 4 * cN1;

  // deterministic mean: same serial sum as the proven K3 (every thread)
  double dsum = 0.0;
  for (int i = 0; i < cNB2; ++i) dsum += dpart[b * cNB2 + i];
  const float meanf = (float)(dsum * (1.0 / (double)cN1));

  // 23 moments over this thread's 16 rows
  double a[23];
  for (int i = 0; i < 23; ++i) a[i] = 0.0;
  for (int it = 0; it < cNB2; ++it) {
    const int n = it * 256 + tid;
    float4 nn = partA[(0 * cB + b) * cN1 + n];   // near4 alias
    float u = (nn.w - meanf - cEPS) * 1e10f;
    float ind = 1.0f / (1.0f + expf(u));
    double di = (double)ind, di2 = di * di;
    double x1 = (double)p1b[n], y1 = (double)p1b[cN1 + n],
           z1 = (double)p1b[2 * cN1 + n];
    double x2 = (double)nn.x, y2 = (double)nn.y, z2 = (double)nn.z;

    a[0] += di;
    a[1] += di * x1;  a[2] += di * y1;  a[3] += di * z1;
    a[4] += di * x2;  a[5] += di * y2;  a[6] += di * z2;
    a[7] += di2;
    a[8]  += di2 * x1;  a[9]  += di2 * y1;  a[10] += di2 * z1;
    a[11] += di2 * x2;  a[12] += di2 * y2;  a[13] += di2 * z2;
    a[14] += di2 * x1 * x2; a[15] += di2 * x1 * y2; a[16] += di2 * x1 * z2;
    a[17] += di2 * y1 * x2; a[18] += di2 * y1 * y2; a[19] += di2 * y1 * z2;
    a[20] += di2 * z1 * x2; a[21] += di2 * z1 * y2; a[22] += di2 * z1 * z2;
  }
  reduce_multi(a, 23, lds, tid);

  // -------- Kabsch solve (Horn quaternion, Jacobi), thread 0 --------
  if (tid != 0) return;

  double W = a[0];
  double c1[3] = {a[1] / W, a[2] / W, a[3] / W};
  double c2[3] = {a[4] / W, a[5] / W, a[6] / W};
  double H[3][3];
  for (int i = 0; i < 3; ++i)
    for (int j = 0; j < 3; ++j)
      H[i][j] = a[14 + 3 * i + j] - c2[j] * a[8 + i] -
                c1[i] * a[11 + j] + c1[i] * c2[j] * a[7];

  // Horn / Besl-McKay 4x4 quaternion matrix -> Jacobi eigen (6 sweeps)
  double trH = H[0][0] + H[1][1] + H[2][2];
  double Nm[4][4], V[4][4];
  Nm[0][0] = trH;
  Nm[0][1] = Nm[1][0] = H[1][2] - H[2][1];
  Nm[0][2] = Nm[2][0] = H[2][0] - H[0][2];
  Nm[0][3] = Nm[3][0] = H[0][1] - H[1][0];
  Nm[1][1] = 2.0 * H[0][0] - trH;
  Nm[1][2] = Nm[2][1] = H[0][1] + H[1][0];
  Nm[1][3] = Nm[3][1] = H[0][2] + H[2][0];
  Nm[2][2] = 2.0 * H[1][1] - trH;
  Nm[2][3] = Nm[3][2] = H[1][2] + H[2][1];
  Nm[3][3] = 2.0 * H[2][2] - trH;

  for (int i = 0; i < 4; ++i)
    for (int j = 0; j < 4; ++j) V[i][j] = (i == j) ? 1.0 : 0.0;

  for (int sweep = 0; sweep < 6; ++sweep) {
    for (int p = 0; p < 3; ++p) {
      for (int q = p + 1; q < 4; ++q) {
        double apq = Nm[p][q];
        if (fabs(apq) < 1e-300) continue;
        double theta = (Nm[q][q] - Nm[p][p]) / (2.0 * apq);
        double tt = (theta >= 0.0 ? 1.0 : -1.0) /
                    (fabs(theta) + sqrt(theta * theta + 1.0));
        double cc = 1.0 / sqrt(tt * tt + 1.0);
        double ss = tt * cc;
        for (int k = 0; k < 4; ++k) {
          double akp = Nm[k][p], akq = Nm[k][q];
          Nm[k][p] = cc * akp - ss * akq;
          Nm[k][q] = ss * akp + cc * akq;
        }
        for (int k = 0; k < 4; ++k) {
          double apk = Nm[p][k], aqk = Nm[q][k];
          Nm[p][k] = cc * apk - ss * aqk;
          Nm[q][k] = ss * apk + cc * aqk;
        }
        for (int k = 0; k < 4; ++k) {
          double vkp = V[k][p], vkq = V[k][q];
          V[k][p] = cc * vkp - ss * vkq;
          V[k][q] = ss * vkp + cc * vkq;
        }
      }
    }
  }
  int imax = 0;
  for (int i = 1; i < 4; ++i)
    if (Nm[i][i] > Nm[imax][imax]) imax = i;
  double qw = V[0][imax], qx = V[1][imax], qy = V[2][imax], qz = V[3][imax];
  double qn = sqrt(qw * qw + qx * qx + qy * qy + qz * qz);
  qw /= qn; qx /= qn; qy /= qn; qz /= qn;

  double R[3][3];
  R[0][0] = 1.0 - 2.0 * (qy * qy + qz * qz);
  R[0][1] = 2.0 * (qx * qy - qw * qz);
  R[0][2] = 2.0 * (qx * qz + qw * qy);
  R[1][0] = 2.0 * (qx * qy + qw * qz);
  R[1][1] = 1.0 - 2.0 * (qx * qx + qz * qz);
  R[1][2] = 2.0 * (qy * qz - qw * qx);
  R[2][0] = 2.0 * (qx * qz - qw * qy);
  R[2][1] = 2.0 * (qy * qz + qw * qx);
  R[2][2] = 1.0 - 2.0 * (qx * qx + qy * qy);

  // safeguard vs convention flip: objective is tr(R H); transpose if better
  double tr1 = 0.0, tr2 = 0.0;
  for (int i = 0; i < 3; ++i)
    for (int j = 0; j < 3; ++j) {
      tr1 += R[i][j] * H[j][i];
      tr2 += R[j][i] * H[j][i];
    }
  if (tr2 > tr1) {
    for (int i = 0; i < 3; ++i)
      for (int j = i + 1; j < 3; ++j) {
        double tmp = R[i][j]; R[i][j] = R[j][i]; R[j][i] = tmp;
      }
  }

  double tx = c2[0] - (R[0][0] * c1[0] + R[0][1] * c1[1] + R[0][2] * c1[2]);
  double ty = c2[1] - (R[1][0] * c1[0] + R[1][1] * c1[1] + R[1][2] * c1[2]);
  double tz = c2[2] - (R[2][0] * c1[0] + R[2][1] * c1[1] + R[2][2] * c1[2]);

  auto sgn = [](double x) { return x >= 0.0 ? 1.0 : -1.0; };
  double oqw = 0.5 * sqrt(fmax(1.0 + R[0][0] + R[1][1] + R[2][2], 1e-12));
  double oqx = 0.5 * sqrt(fmax(1.0 + R[0][0] - R[1][1] - R[2][2], 1e-12)) *
               sgn(R[2][1] - R[1][2]);
  double oqy = 0.5 * sqrt(fmax(1.0 - R[0][0] + R[1][1] - R[2][2], 1e-12)) *
               sgn(R[0][2] - R[2][0]);
  double oqz = 0.5 * sqrt(fmax(1.0 - R[0][0] - R[1][1] + R[2][2], 1e-12)) *
               sgn(R[1][0] - R[0][1]);

  float* T = out + b * 16;
  T[0]  = (float)R[0][0]; T[1]  = (float)R[0][1]; T[2]  = (float)R[0][2]; T[3]  = (float)tx;
  T[4]  = (float)R[1][0]; T[5]  = (float)R[1][1]; T[6]  = (float)R[1][2]; T[7]  = (float)ty;
  T[8]  = (float)R[2][0]; T[9]  = (float)R[2][1]; T[10] = (float)R[2][2]; T[11] = (float)tz;
  T[12] = 0.f; T[13] = 0.f; T[14] = 0.f; T[15] = 1.f;
  float* Q = out + 128 + b * 4;
  Q[0] = (float)oqw; Q[1] = (float)oqx; Q[2] = (float)oqy; Q[3] = (float)oqz;
  float* Tt = out + 160 + b * 3;
  Tt[0] = (float)tx; Tt[1] = (float)ty; Tt[2] = (float)tz;
}

// ---------------- launch ----------------
extern "C" void kernel_launch(void* const* d_in, const int* in_sizes, int n_in,
                              void* d_out, int out_size, void* d_ws, size_t ws_size,
                              hipStream_t stream) {
  const float* pc1 = (const float*)d_in[0];
  const float* pc2 = (const float*)d_in[1];
  float* out = (float*)d_out;
  char* ws = (char*)d_ws;

  float4* partA = (float4*)ws;
  float*  partM = (float*)(ws + OFF_PARTM);
  double* dpart = (double*)(ws + OFF_DPART);

  cpnet_partial<<<dim3(cN1 / cROWS, cMC, cB), 256, 0, stream>>>(pc1, pc2,
                                                                partA, partM);
  cpnet_combine<<<dim3(cNB2, cB), 256, 0, stream>>>(pc1, partA, partM, dpart);
  cpnet_moments_solve<<<cB, 256, 0, stream>>>(pc1, partA, dpart, out);
}